// Round 1
// baseline (183.055 us; speedup 1.0000x reference)
//
#include <hip/hip_runtime.h>
#include <math.h>

#define NB   8
#define CIN  256
#define CMID 16
#define NH   128
#define NW   128
#define HWSZ 16384
#define NANG 8
#define NRAD 9

__device__ __forceinline__ int bitrev7(int v) {
    return (int)(__brev((unsigned)v) >> 25);
}

// Gain in bit-reversed (both dims), ifftshift-folded order, pre-scaled by 1/16384.
__global__ void __launch_bounds__(256) gain_kernel(const float* __restrict__ fw,
                                                   float* __restrict__ gain) {
    int p  = blockIdx.x * 256 + threadIdx.x;      // storage index (py,px)
    int py = p >> 7, px = p & 127;
    int fy = bitrev7(py), fx = bitrev7(px);       // natural frequency index
    int hy = (fy + 64) & 127, hx = (fx + 64) & 127; // shifted-pixel coords
    float dy = (float)(hy - 64), dx = (float)(hx - 64);
    float r = sqrtf(dy * dy + dx * dx);
    int ridx = (int)floorf(r * 0.125f);
    if (ridx > NRAD - 1) ridx = NRAD - 1;
    const float PI_F = 3.14159265358979323846f;   // rounds to float32 pi
    float theta = fmodf(atan2f(dy, dx) + PI_F, PI_F);
    const float delta = (float)(M_PI / 8.0);
    const float hwid  = (float)(1.5 * (M_PI / 8.0) / 2.0);
    float wv[NANG];
    float wsum = 0.f;
#pragma unroll
    for (int a = 0; a < NANG; ++a) {
        float c = ((float)a + 0.5f) * delta;
        float dist = fabsf(theta - c);
        float wa = fmaxf(1.0f - dist / hwid, 0.0f);
        if (!(dist < hwid)) wa = 0.0f;
        wv[a] = wa;
        wsum += wa;
    }
    float inv = 1.0f / (wsum + 1e-8f);
#pragma unroll
    for (int m = 0; m < CMID; ++m) {
        float g = 0.f;
#pragma unroll
        for (int a = 0; a < NANG; ++a)
            g += wv[a] * fw[(m * NANG + a) * NRAD + ridx];
        gain[m * HWSZ + p] = g * inv * (1.0f / 16384.0f);
    }
}

// x (B,C,H,W) -> xp (B,16,H,W): thread per float2 of pixels; uniform c-loop -> s_loads for w_in.
__global__ void __launch_bounds__(256) proj_kernel(const float* __restrict__ x,
                                                   const float* __restrict__ w_in,
                                                   float* __restrict__ xp) {
    int b  = blockIdx.y;
    int p2 = blockIdx.x * 256 + threadIdx.x;      // float2 index, HWSZ/2 per image
    const float2* xb = (const float2*)(x + (size_t)b * CIN * HWSZ);
    float2 acc[CMID];
#pragma unroll
    for (int m = 0; m < CMID; ++m) acc[m] = make_float2(0.f, 0.f);
#pragma unroll 4
    for (int c = 0; c < CIN; ++c) {
        float2 v = xb[c * (HWSZ / 2) + p2];
#pragma unroll
        for (int m = 0; m < CMID; ++m) {
            float wm = w_in[m * CIN + c];
            acc[m].x = fmaf(v.x, wm, acc[m].x);
            acc[m].y = fmaf(v.y, wm, acc[m].y);
        }
    }
    float2* xpb = (float2*)(xp + (size_t)b * CMID * HWSZ);
#pragma unroll
    for (int m = 0; m < CMID; ++m) xpb[m * (HWSZ / 2) + p2] = acc[m];
}

// One block per (b,m) image. Whole image in LDS (128 KiB). Forward DIF (rows, cols)
// -> bit-reversed spectrum; multiply pre-permuted gain; inverse DIT (cols, rows) -> natural.
// In-place: reads io[image], writes real part back to io[image].
__global__ void __launch_bounds__(256) fft_kernel(float* __restrict__ io,
                                                  const float* __restrict__ gain) {
    __shared__ float2 img[HWSZ];                  // 128 KiB
    int image = blockIdx.x;                       // b*CMID + m
    int m = image & (CMID - 1);
    int t = threadIdx.x;
    float* src = io + (size_t)image * HWSZ;
    for (int i = t; i < HWSZ; i += 256) img[i] = make_float2(src[i], 0.f);
    __syncthreads();
    const float PI_F = 3.14159265358979323846f;

    // ---- forward rows (DIF): lane -> butterfly j, wave group -> rows ----
    {
        int j = t & 63;
        int rb = t >> 6;                          // 0..3
        for (int ls = 6; ls >= 0; --ls) {
            int s = 1 << ls;
            int off = j & (s - 1);
            int i0 = ((j >> ls) << (ls + 1)) + off;
            float ang = -PI_F * (float)off / (float)s;
            float sn, cs;
            __sincosf(ang, &sn, &cs);
            for (int r = rb; r < NH; r += 4) {
                float2 a = img[r * NW + i0];
                float2 bb = img[r * NW + i0 + s];
                img[r * NW + i0] = make_float2(a.x + bb.x, a.y + bb.y);
                float dx_ = a.x - bb.x, dy_ = a.y - bb.y;
                img[r * NW + i0 + s] = make_float2(dx_ * cs - dy_ * sn, dx_ * sn + dy_ * cs);
            }
            __syncthreads();
        }
    }
    // ---- forward cols (DIF): lane -> column (bank-friendly), loop butterflies ----
    {
        int col = t & 127;
        int jb = t >> 7;                          // 0..1
        for (int ls = 6; ls >= 0; --ls) {
            int s = 1 << ls;
            for (int j = jb; j < 64; j += 2) {
                int off = j & (s - 1);
                int i0 = ((j >> ls) << (ls + 1)) + off;
                float ang = -PI_F * (float)off / (float)s;
                float sn, cs;
                __sincosf(ang, &sn, &cs);
                float2 a = img[i0 * NW + col];
                float2 bb = img[(i0 + s) * NW + col];
                img[i0 * NW + col] = make_float2(a.x + bb.x, a.y + bb.y);
                float dx_ = a.x - bb.x, dy_ = a.y - bb.y;
                img[(i0 + s) * NW + col] = make_float2(dx_ * cs - dy_ * sn, dx_ * sn + dy_ * cs);
            }
            __syncthreads();
        }
    }
    // ---- gain multiply (gain already bit-rev permuted + 1/16384) ----
    {
        const float* gm = gain + (size_t)m * HWSZ;
        for (int i = t; i < HWSZ; i += 256) {
            float g = gm[i];
            img[i].x *= g;
            img[i].y *= g;
        }
        __syncthreads();
    }
    // ---- inverse cols (DIT) ----
    {
        int col = t & 127;
        int jb = t >> 7;
        for (int ls = 0; ls <= 6; ++ls) {
            int s = 1 << ls;
            for (int j = jb; j < 64; j += 2) {
                int off = j & (s - 1);
                int i0 = ((j >> ls) << (ls + 1)) + off;
                float ang = PI_F * (float)off / (float)s;
                float sn, cs;
                __sincosf(ang, &sn, &cs);
                float2 a = img[i0 * NW + col];
                float2 bb = img[(i0 + s) * NW + col];
                float tx = bb.x * cs - bb.y * sn, ty = bb.x * sn + bb.y * cs;
                img[i0 * NW + col] = make_float2(a.x + tx, a.y + ty);
                img[(i0 + s) * NW + col] = make_float2(a.x - tx, a.y - ty);
            }
            __syncthreads();
        }
    }
    // ---- inverse rows (DIT) ----
    {
        int j = t & 63;
        int rb = t >> 6;
        for (int ls = 0; ls <= 6; ++ls) {
            int s = 1 << ls;
            int off = j & (s - 1);
            int i0 = ((j >> ls) << (ls + 1)) + off;
            float ang = PI_F * (float)off / (float)s;
            float sn, cs;
            __sincosf(ang, &sn, &cs);
            for (int r = rb; r < NH; r += 4) {
                float2 a = img[r * NW + i0];
                float2 bb = img[r * NW + i0 + s];
                float tx = bb.x * cs - bb.y * sn, ty = bb.x * sn + bb.y * cs;
                img[r * NW + i0] = make_float2(a.x + tx, a.y + ty);
                img[r * NW + i0 + s] = make_float2(a.x - tx, a.y - ty);
            }
            __syncthreads();
        }
    }
    for (int i = t; i < HWSZ; i += 256) src[i] = img[i].x;
}

// out = x + w_out * x_enh: thread per pixel, 16 x_enh in registers, uniform c-loop -> s_loads.
__global__ void __launch_bounds__(256) out_kernel(const float* __restrict__ x,
                                                  const float* __restrict__ w_out,
                                                  const float* __restrict__ xe,
                                                  float* __restrict__ out) {
    int b = blockIdx.y;
    int p = blockIdx.x * 256 + threadIdx.x;
    const float* xeb = xe + (size_t)b * CMID * HWSZ;
    float e[CMID];
#pragma unroll
    for (int m = 0; m < CMID; ++m) e[m] = xeb[m * HWSZ + p];
    const float* xb = x + (size_t)b * CIN * HWSZ;
    float* ob = out + (size_t)b * CIN * HWSZ;
#pragma unroll 2
    for (int c = 0; c < CIN; ++c) {
        float acc = xb[c * HWSZ + p];
#pragma unroll
        for (int m = 0; m < CMID; ++m)
            acc = fmaf(w_out[c * CMID + m], e[m], acc);
        ob[c * HWSZ + p] = acc;
    }
}

extern "C" void kernel_launch(void* const* d_in, const int* in_sizes, int n_in,
                              void* d_out, int out_size, void* d_ws, size_t ws_size,
                              hipStream_t stream) {
    const float* x     = (const float*)d_in[0];
    const float* w_in  = (const float*)d_in[1];
    const float* w_out = (const float*)d_in[2];
    const float* fw    = (const float*)d_in[3];
    float* out = (float*)d_out;
    float* ws  = (float*)d_ws;
    float* xp   = ws;                       // B*CMID*HWSZ floats = 8 MiB (also holds x_enh in-place)
    float* gain = ws + (size_t)NB * CMID * HWSZ;  // CMID*HWSZ floats = 1 MiB

    gain_kernel<<<HWSZ / 256, 256, 0, stream>>>(fw, gain);
    proj_kernel<<<dim3(HWSZ / 2 / 256, NB), 256, 0, stream>>>(x, w_in, xp);
    fft_kernel<<<NB * CMID, 256, 0, stream>>>(xp, gain);
    out_kernel<<<dim3(HWSZ / 256, NB), 256, 0, stream>>>(x, w_out, xp, out);
}

// Round 2
// 180.047 us; speedup vs baseline: 1.0167x; 1.0167x over previous
//
#include <hip/hip_runtime.h>
#include <math.h>

#define NB   8
#define CIN  256
#define CMID 16
#define NH   128
#define NW   128
#define HWSZ 16384
#define NANG 8
#define NRAD 9

__device__ __forceinline__ int bitrev7(int v) {
    return (int)(__brev((unsigned)v) >> 25);
}

// Gain in bit-reversed (both dims), ifftshift-folded order, pre-scaled by 1/16384.
__global__ void __launch_bounds__(256) gain_kernel(const float* __restrict__ fw,
                                                   float* __restrict__ gain) {
    int p  = blockIdx.x * 256 + threadIdx.x;      // storage index (py,px)
    int py = p >> 7, px = p & 127;
    int fy = bitrev7(py), fx = bitrev7(px);       // natural frequency index
    int hy = (fy + 64) & 127, hx = (fx + 64) & 127; // shifted-pixel coords
    float dy = (float)(hy - 64), dx = (float)(hx - 64);
    float r = sqrtf(dy * dy + dx * dx);
    int ridx = (int)floorf(r * 0.125f);
    if (ridx > NRAD - 1) ridx = NRAD - 1;
    const float PI_F = 3.14159265358979323846f;
    float theta = fmodf(atan2f(dy, dx) + PI_F, PI_F);
    const float delta = (float)(M_PI / 8.0);
    const float hwid  = (float)(1.5 * (M_PI / 8.0) / 2.0);
    float wv[NANG];
    float wsum = 0.f;
#pragma unroll
    for (int a = 0; a < NANG; ++a) {
        float c = ((float)a + 0.5f) * delta;
        float dist = fabsf(theta - c);
        float wa = fmaxf(1.0f - dist / hwid, 0.0f);
        if (!(dist < hwid)) wa = 0.0f;
        wv[a] = wa;
        wsum += wa;
    }
    float inv = 1.0f / (wsum + 1e-8f);
#pragma unroll
    for (int m = 0; m < CMID; ++m) {
        float g = 0.f;
#pragma unroll
        for (int a = 0; a < NANG; ++a)
            g += wv[a] * fw[(m * NANG + a) * NRAD + ridx];
        gain[m * HWSZ + p] = g * inv * (1.0f / 16384.0f);
    }
}

// P1: proj (256->16) fused with forward row-DIF FFT.
// Block = (b, 2 rows). 256 threads, thread t owns pixel p=t of the 2x128 strip.
// Writes row-spectra (px bit-reversed) to xf[(b*16+m)*HWSZ + r0*128 + p] as float2.
__global__ void __launch_bounds__(256) proj_fft_rows(const float* __restrict__ x,
                                                     const float* __restrict__ w_in,
                                                     float2* __restrict__ xf) {
    __shared__ float2 img[CMID * 256];            // [m][p], 32 KB
    int b  = blockIdx.y;
    int r0 = blockIdx.x * 2;
    int t  = threadIdx.x;
    const float* xb = x + (size_t)b * CIN * HWSZ + r0 * NW;

    float acc[CMID];
#pragma unroll
    for (int m = 0; m < CMID; ++m) acc[m] = 0.f;
#pragma unroll 8
    for (int c = 0; c < CIN; ++c) {
        float v = xb[(size_t)c * HWSZ + t];
#pragma unroll
        for (int m = 0; m < CMID; ++m)
            acc[m] = fmaf(v, w_in[m * CIN + c], acc[m]);
    }
#pragma unroll
    for (int m = 0; m < CMID; ++m) img[m * 256 + t] = make_float2(acc[m], 0.f);
    __syncthreads();

    const float PI_F = 3.14159265358979323846f;
    // 32 independent 128-pt FFTs (16 m x 2 rows), flat rows of 128 at img + f*128.
    int j  = t & 63;
    int fb = t >> 6;                              // 0..3
    for (int ls = 6; ls >= 0; --ls) {
        int s = 1 << ls;
        int off = j & (s - 1);
        int i0 = ((j >> ls) << (ls + 1)) + off;
        float ang = -PI_F * (float)off / (float)s;
        float sn, cs;
        __sincosf(ang, &sn, &cs);
        for (int f = fb; f < 32; f += 4) {
            float2* row = img + f * 128;
            float2 a = row[i0];
            float2 bb = row[i0 + s];
            row[i0] = make_float2(a.x + bb.x, a.y + bb.y);
            float dx_ = a.x - bb.x, dy_ = a.y - bb.y;
            row[i0 + s] = make_float2(dx_ * cs - dy_ * sn, dx_ * sn + dy_ * cs);
        }
        __syncthreads();
    }
#pragma unroll
    for (int m = 0; m < CMID; ++m)
        xf[((size_t)(b * CMID + m)) * HWSZ + r0 * NW + t] = img[m * 256 + t];
}

// P2: forward col-DIF + gain + inverse col-DIT, fused. Block = (image, 32-col tile).
// LDS tile [128 rows][33 cols] (pad kills bank conflicts).
__global__ void __launch_bounds__(256) fft_cols_gain(float2* __restrict__ xf,
                                                     const float* __restrict__ gain) {
    __shared__ float2 buf[128 * 33];              // 33.8 KB
    int img = blockIdx.y;                         // b*16 + m
    int m   = img & (CMID - 1);
    int c0  = blockIdx.x * 32;
    int t   = threadIdx.x;
    float2* xi = xf + (size_t)img * HWSZ;

    for (int idx = t; idx < 128 * 32; idx += 256) {
        int r = idx >> 5, lc = idx & 31;
        buf[r * 33 + lc] = xi[r * NW + c0 + lc];
    }
    __syncthreads();

    const float PI_F = 3.14159265358979323846f;
    int lc = t & 31;
    int jb = t >> 5;                              // 0..7
    // forward col DIF
    for (int ls = 6; ls >= 0; --ls) {
        int s = 1 << ls;
        for (int j = jb; j < 64; j += 8) {
            int off = j & (s - 1);
            int i0 = ((j >> ls) << (ls + 1)) + off;
            float ang = -PI_F * (float)off / (float)s;
            float sn, cs;
            __sincosf(ang, &sn, &cs);
            float2 a = buf[i0 * 33 + lc];
            float2 bb = buf[(i0 + s) * 33 + lc];
            buf[i0 * 33 + lc] = make_float2(a.x + bb.x, a.y + bb.y);
            float dx_ = a.x - bb.x, dy_ = a.y - bb.y;
            buf[(i0 + s) * 33 + lc] = make_float2(dx_ * cs - dy_ * sn, dx_ * sn + dy_ * cs);
        }
        __syncthreads();
    }
    // gain (pre-permuted double-bitrev, pre-scaled 1/16384)
    {
        const float* gm = gain + (size_t)m * HWSZ;
        for (int idx = t; idx < 128 * 32; idx += 256) {
            int r = idx >> 5, lcc = idx & 31;
            float g = gm[r * NW + c0 + lcc];
            buf[r * 33 + lcc].x *= g;
            buf[r * 33 + lcc].y *= g;
        }
        __syncthreads();
    }
    // inverse col DIT
    for (int ls = 0; ls <= 6; ++ls) {
        int s = 1 << ls;
        for (int j = jb; j < 64; j += 8) {
            int off = j & (s - 1);
            int i0 = ((j >> ls) << (ls + 1)) + off;
            float ang = PI_F * (float)off / (float)s;
            float sn, cs;
            __sincosf(ang, &sn, &cs);
            float2 a = buf[i0 * 33 + lc];
            float2 bb = buf[(i0 + s) * 33 + lc];
            float tx = bb.x * cs - bb.y * sn, ty = bb.x * sn + bb.y * cs;
            buf[i0 * 33 + lc] = make_float2(a.x + tx, a.y + ty);
            buf[(i0 + s) * 33 + lc] = make_float2(a.x - tx, a.y - ty);
        }
        __syncthreads();
    }
    for (int idx = t; idx < 128 * 32; idx += 256) {
        int r = idx >> 5, lcc = idx & 31;
        xi[r * NW + c0 + lcc] = buf[r * 33 + lcc];
    }
}

// P3: inverse row-DIT fused with out = x + w_out * x_enh.
// Block = (b, 2 rows), all 16 m staged in LDS; e[m] hoisted to registers.
__global__ void __launch_bounds__(256) ifft_rows_out(const float2* __restrict__ xf,
                                                     const float* __restrict__ x,
                                                     const float* __restrict__ w_out,
                                                     float* __restrict__ out) {
    __shared__ float2 img[CMID * 256];            // 32 KB
    int b  = blockIdx.y;
    int r0 = blockIdx.x * 2;
    int t  = threadIdx.x;

#pragma unroll
    for (int m = 0; m < CMID; ++m)
        img[m * 256 + t] = xf[((size_t)(b * CMID + m)) * HWSZ + r0 * NW + t];
    __syncthreads();

    const float PI_F = 3.14159265358979323846f;
    int j  = t & 63;
    int fb = t >> 6;
    for (int ls = 0; ls <= 6; ++ls) {
        int s = 1 << ls;
        int off = j & (s - 1);
        int i0 = ((j >> ls) << (ls + 1)) + off;
        float ang = PI_F * (float)off / (float)s;
        float sn, cs;
        __sincosf(ang, &sn, &cs);
        for (int f = fb; f < 32; f += 4) {
            float2* row = img + f * 128;
            float2 a = row[i0];
            float2 bb = row[i0 + s];
            float tx = bb.x * cs - bb.y * sn, ty = bb.x * sn + bb.y * cs;
            row[i0] = make_float2(a.x + tx, a.y + ty);
            row[i0 + s] = make_float2(a.x - tx, a.y - ty);
        }
        __syncthreads();
    }

    float e[CMID];
#pragma unroll
    for (int m = 0; m < CMID; ++m) e[m] = img[m * 256 + t].x;

    const float* xb = x + (size_t)b * CIN * HWSZ + r0 * NW;
    float* ob = out + (size_t)b * CIN * HWSZ + r0 * NW;
#pragma unroll 4
    for (int c = 0; c < CIN; ++c) {
        float acc = xb[(size_t)c * HWSZ + t];
#pragma unroll
        for (int m = 0; m < CMID; ++m)
            acc = fmaf(w_out[c * CMID + m], e[m], acc);
        ob[(size_t)c * HWSZ + t] = acc;
    }
}

extern "C" void kernel_launch(void* const* d_in, const int* in_sizes, int n_in,
                              void* d_out, int out_size, void* d_ws, size_t ws_size,
                              hipStream_t stream) {
    const float* x     = (const float*)d_in[0];
    const float* w_in  = (const float*)d_in[1];
    const float* w_out = (const float*)d_in[2];
    const float* fw    = (const float*)d_in[3];
    float* out = (float*)d_out;
    float* ws  = (float*)d_ws;
    float2* xf  = (float2*)ws;                              // B*16*HWSZ complex = 16.8 MB
    float*  gain = ws + (size_t)NB * CMID * HWSZ * 2;       // 16*HWSZ floats = 1 MB

    gain_kernel<<<HWSZ / 256, 256, 0, stream>>>(fw, gain);
    proj_fft_rows<<<dim3(NH / 2, NB), 256, 0, stream>>>(x, w_in, xf);
    fft_cols_gain<<<dim3(NW / 32, NB * CMID), 256, 0, stream>>>(xf, gain);
    ifft_rows_out<<<dim3(NH / 2, NB), 256, 0, stream>>>(xf, x, w_out, out);
}

// Round 3
// 134.765 us; speedup vs baseline: 1.3583x; 1.3360x over previous
//
#include <hip/hip_runtime.h>
#include <math.h>

#define NB   8
#define CIN  256
#define CMID 16
#define NH   128
#define NW   128
#define HWSZ 16384
#define NANG 8
#define NRAD 9

__device__ __forceinline__ int bitrev7(int v) {
    return (int)(__brev((unsigned)v) >> 25);
}

// Gain in bit-reversed (both dims), ifftshift-folded order, pre-scaled by 1/16384.
__global__ void __launch_bounds__(256) gain_kernel(const float* __restrict__ fw,
                                                   float* __restrict__ gain) {
    int p  = blockIdx.x * 256 + threadIdx.x;
    int py = p >> 7, px = p & 127;
    int fy = bitrev7(py), fx = bitrev7(px);
    int hy = (fy + 64) & 127, hx = (fx + 64) & 127;
    float dy = (float)(hy - 64), dx = (float)(hx - 64);
    float r = sqrtf(dy * dy + dx * dx);
    int ridx = (int)floorf(r * 0.125f);
    if (ridx > NRAD - 1) ridx = NRAD - 1;
    const float PI_F = 3.14159265358979323846f;
    float theta = fmodf(atan2f(dy, dx) + PI_F, PI_F);
    const float delta = (float)(M_PI / 8.0);
    const float hwid  = (float)(1.5 * (M_PI / 8.0) / 2.0);
    float wv[NANG];
    float wsum = 0.f;
#pragma unroll
    for (int a = 0; a < NANG; ++a) {
        float c = ((float)a + 0.5f) * delta;
        float dist = fabsf(theta - c);
        float wa = fmaxf(1.0f - dist / hwid, 0.0f);
        if (!(dist < hwid)) wa = 0.0f;
        wv[a] = wa;
        wsum += wa;
    }
    float inv = 1.0f / (wsum + 1e-8f);
#pragma unroll
    for (int m = 0; m < CMID; ++m) {
        float g = 0.f;
#pragma unroll
        for (int a = 0; a < NANG; ++a)
            g += wv[a] * fw[(m * NANG + a) * NRAD + ridx];
        gain[m * HWSZ + p] = g * inv * (1.0f / 16384.0f);
    }
}

// K2: split-K projection. Block = (px-tile of 512 px as float2, chunk, b).
// Writes partials[(b*nchunk+ck)*16+m][HWSZ].
__global__ void __launch_bounds__(256, 4) proj_partial(const float* __restrict__ x,
                                                       const float* __restrict__ w_in,
                                                       float* __restrict__ partials,
                                                       int nchunk) {
    int b  = blockIdx.z;
    int ck = blockIdx.y;
    int p2 = blockIdx.x * 256 + threadIdx.x;          // float2 index, 8192/image
    int cpc = CIN / nchunk;
    int c0 = ck * cpc;
    const float2* xb = (const float2*)(x + (size_t)b * CIN * HWSZ);
    float2 acc[CMID];
#pragma unroll
    for (int m = 0; m < CMID; ++m) acc[m] = make_float2(0.f, 0.f);
#pragma unroll 4
    for (int c = c0; c < c0 + cpc; ++c) {
        float2 v = xb[(size_t)c * (HWSZ / 2) + p2];
#pragma unroll
        for (int m = 0; m < CMID; ++m) {
            float wm = w_in[m * CIN + c];
            acc[m].x = fmaf(v.x, wm, acc[m].x);
            acc[m].y = fmaf(v.y, wm, acc[m].y);
        }
    }
    float2* pb = (float2*)(partials + ((size_t)(b * nchunk + ck) * CMID) * HWSZ);
#pragma unroll
    for (int m = 0; m < CMID; ++m) pb[(size_t)m * (HWSZ / 2) + p2] = acc[m];
}

// K3: reduce nchunk partials + forward row-DIF FFT. Block = 4 rows of one (b,m) image.
__global__ void __launch_bounds__(256) reduce_fft_rows(const float* __restrict__ partials,
                                                       float2* __restrict__ xf,
                                                       int nchunk) {
    __shared__ float2 lds[4 * 128];                   // 4 KB
    int img = blockIdx.y;                             // b*16 + m
    int b = img >> 4, m = img & 15;
    int r0 = blockIdx.x * 4;
    int t = threadIdx.x;
#pragma unroll
    for (int ii = 0; ii < 2; ++ii) {
        int px = ii * 256 + t;                        // 0..511 within 4x128 strip
        float s = 0.f;
        for (int ck = 0; ck < nchunk; ++ck)
            s += partials[((size_t)(b * nchunk + ck) * CMID + m) * HWSZ + r0 * NW + px];
        lds[px] = make_float2(s, 0.f);
    }
    __syncthreads();
    const float PI_F = 3.14159265358979323846f;
    int j = t & 63;
    float2* row = lds + (t >> 6) * 128;               // one FFT per quarter-wave group
    for (int ls = 6; ls >= 0; --ls) {
        int s = 1 << ls;
        int off = j & (s - 1);
        int i0 = ((j >> ls) << (ls + 1)) + off;
        float ang = -PI_F * (float)off / (float)s;
        float sn, cs;
        __sincosf(ang, &sn, &cs);
        float2 a = row[i0];
        float2 bb = row[i0 + s];
        row[i0] = make_float2(a.x + bb.x, a.y + bb.y);
        float dx_ = a.x - bb.x, dy_ = a.y - bb.y;
        row[i0 + s] = make_float2(dx_ * cs - dy_ * sn, dx_ * sn + dy_ * cs);
        __syncthreads();
    }
#pragma unroll
    for (int ii = 0; ii < 2; ++ii) {
        int px = ii * 256 + t;
        xf[(size_t)img * HWSZ + r0 * NW + px] = lds[px];
    }
}

// K4: forward col-DIF + gain + inverse col-DIT (proven in R2). Block = (32-col tile, image).
__global__ void __launch_bounds__(256) fft_cols_gain(float2* __restrict__ xf,
                                                     const float* __restrict__ gain) {
    __shared__ float2 buf[128 * 33];
    int img = blockIdx.y;
    int m   = img & (CMID - 1);
    int c0  = blockIdx.x * 32;
    int t   = threadIdx.x;
    float2* xi = xf + (size_t)img * HWSZ;

    for (int idx = t; idx < 128 * 32; idx += 256) {
        int r = idx >> 5, lc = idx & 31;
        buf[r * 33 + lc] = xi[r * NW + c0 + lc];
    }
    __syncthreads();
    const float PI_F = 3.14159265358979323846f;
    int lc = t & 31;
    int jb = t >> 5;
    for (int ls = 6; ls >= 0; --ls) {
        int s = 1 << ls;
        for (int j = jb; j < 64; j += 8) {
            int off = j & (s - 1);
            int i0 = ((j >> ls) << (ls + 1)) + off;
            float ang = -PI_F * (float)off / (float)s;
            float sn, cs;
            __sincosf(ang, &sn, &cs);
            float2 a = buf[i0 * 33 + lc];
            float2 bb = buf[(i0 + s) * 33 + lc];
            buf[i0 * 33 + lc] = make_float2(a.x + bb.x, a.y + bb.y);
            float dx_ = a.x - bb.x, dy_ = a.y - bb.y;
            buf[(i0 + s) * 33 + lc] = make_float2(dx_ * cs - dy_ * sn, dx_ * sn + dy_ * cs);
        }
        __syncthreads();
    }
    {
        const float* gm = gain + (size_t)m * HWSZ;
        for (int idx = t; idx < 128 * 32; idx += 256) {
            int r = idx >> 5, lcc = idx & 31;
            float g = gm[r * NW + c0 + lcc];
            buf[r * 33 + lcc].x *= g;
            buf[r * 33 + lcc].y *= g;
        }
        __syncthreads();
    }
    for (int ls = 0; ls <= 6; ++ls) {
        int s = 1 << ls;
        for (int j = jb; j < 64; j += 8) {
            int off = j & (s - 1);
            int i0 = ((j >> ls) << (ls + 1)) + off;
            float ang = PI_F * (float)off / (float)s;
            float sn, cs;
            __sincosf(ang, &sn, &cs);
            float2 a = buf[i0 * 33 + lc];
            float2 bb = buf[(i0 + s) * 33 + lc];
            float tx = bb.x * cs - bb.y * sn, ty = bb.x * sn + bb.y * cs;
            buf[i0 * 33 + lc] = make_float2(a.x + tx, a.y + ty);
            buf[(i0 + s) * 33 + lc] = make_float2(a.x - tx, a.y - ty);
        }
        __syncthreads();
    }
    for (int idx = t; idx < 128 * 32; idx += 256) {
        int r = idx >> 5, lcc = idx & 31;
        xi[r * NW + c0 + lcc] = buf[r * 33 + lcc];
    }
}

// K5: inverse row-DIT, write real x_enh. Block = 4 rows of one image.
__global__ void __launch_bounds__(256) ifft_rows(const float2* __restrict__ xf,
                                                 float* __restrict__ xe) {
    __shared__ float2 lds[4 * 128];
    int img = blockIdx.y;
    int r0 = blockIdx.x * 4;
    int t = threadIdx.x;
#pragma unroll
    for (int ii = 0; ii < 2; ++ii) {
        int px = ii * 256 + t;
        lds[px] = xf[(size_t)img * HWSZ + r0 * NW + px];
    }
    __syncthreads();
    const float PI_F = 3.14159265358979323846f;
    int j = t & 63;
    float2* row = lds + (t >> 6) * 128;
    for (int ls = 0; ls <= 6; ++ls) {
        int s = 1 << ls;
        int off = j & (s - 1);
        int i0 = ((j >> ls) << (ls + 1)) + off;
        float ang = PI_F * (float)off / (float)s;
        float sn, cs;
        __sincosf(ang, &sn, &cs);
        float2 a = row[i0];
        float2 bb = row[i0 + s];
        float tx = bb.x * cs - bb.y * sn, ty = bb.x * sn + bb.y * cs;
        row[i0] = make_float2(a.x + tx, a.y + ty);
        row[i0 + s] = make_float2(a.x - tx, a.y - ty);
        __syncthreads();
    }
#pragma unroll
    for (int ii = 0; ii < 2; ++ii) {
        int px = ii * 256 + t;
        xe[(size_t)img * HWSZ + r0 * NW + px] = lds[px].x;
    }
}

// K6: out = x + w_out * x_enh. Block = (px-tile 512 as float2, c-tile 64, b).
// e[16] held in registers (xe re-read per c-tile, L2/L3-resident).
__global__ void __launch_bounds__(256, 4) out_kernel(const float* __restrict__ x,
                                                     const float* __restrict__ w_out,
                                                     const float* __restrict__ xe,
                                                     float* __restrict__ out) {
    int b  = blockIdx.z;
    int ct = blockIdx.y;
    int p2 = blockIdx.x * 256 + threadIdx.x;
    const float2* xeb = (const float2*)(xe + (size_t)b * CMID * HWSZ);
    float2 e[CMID];
#pragma unroll
    for (int m = 0; m < CMID; ++m) e[m] = xeb[(size_t)m * (HWSZ / 2) + p2];
    const float2* xb = (const float2*)(x + (size_t)b * CIN * HWSZ);
    float2* ob = (float2*)(out + (size_t)b * CIN * HWSZ);
    int c0 = ct * (CIN / 4);
#pragma unroll 4
    for (int c = c0; c < c0 + CIN / 4; ++c) {
        float2 acc = xb[(size_t)c * (HWSZ / 2) + p2];
#pragma unroll
        for (int m = 0; m < CMID; ++m) {
            float wm = w_out[c * CMID + m];
            acc.x = fmaf(wm, e[m].x, acc.x);
            acc.y = fmaf(wm, e[m].y, acc.y);
        }
        ob[(size_t)c * (HWSZ / 2) + p2] = acc;
    }
}

extern "C" void kernel_launch(void* const* d_in, const int* in_sizes, int n_in,
                              void* d_out, int out_size, void* d_ws, size_t ws_size,
                              hipStream_t stream) {
    const float* x     = (const float*)d_in[0];
    const float* w_in  = (const float*)d_in[1];
    const float* w_out = (const float*)d_in[2];
    const float* fw    = (const float*)d_in[3];
    float* out = (float*)d_out;
    float* ws  = (float*)d_ws;

    // ws layout: [partials: nchunk*8.4MB | xf: 16.8MB | gain: 1MB]; xe aliases partials.
    int nchunk = 4;
    while (nchunk > 1) {
        size_t need = ((size_t)NB * nchunk * CMID * HWSZ +
                       (size_t)NB * CMID * HWSZ * 2 + (size_t)CMID * HWSZ) * sizeof(float);
        if (need <= ws_size) break;
        nchunk >>= 1;
    }
    float*  partials = ws;
    float2* xf   = (float2*)(ws + (size_t)NB * nchunk * CMID * HWSZ);
    float*  gain = (float*)(xf + (size_t)NB * CMID * HWSZ);
    float*  xe   = partials;                          // reuse after K3 consumes partials

    gain_kernel<<<HWSZ / 256, 256, 0, stream>>>(fw, gain);
    proj_partial<<<dim3(HWSZ / 2 / 256, nchunk, NB), 256, 0, stream>>>(x, w_in, partials, nchunk);
    reduce_fft_rows<<<dim3(NH / 4, NB * CMID), 256, 0, stream>>>(partials, xf, nchunk);
    fft_cols_gain<<<dim3(NW / 32, NB * CMID), 256, 0, stream>>>(xf, gain);
    ifft_rows<<<dim3(NH / 4, NB * CMID), 256, 0, stream>>>(xf, xe);
    out_kernel<<<dim3(HWSZ / 2 / 256, 4, NB), 256, 0, stream>>>(x, w_out, xe, out);
}

// Round 5
// 131.078 us; speedup vs baseline: 1.3965x; 1.0281x over previous
//
#include <hip/hip_runtime.h>
#include <math.h>

#define NB   8
#define CIN  256
#define CMID 16
#define NH   128
#define NW   128
#define HWSZ 16384
#define HW4  4096
#define NANG 8
#define NRAD 9

typedef float f32x4_t __attribute__((ext_vector_type(4)));

__device__ __forceinline__ int bitrev7(int v) {
    return (int)(__brev((unsigned)v) >> 25);
}

// Gain in bit-reversed (both dims), ifftshift-folded order, pre-scaled by 1/16384.
__global__ void __launch_bounds__(256) gain_kernel(const float* __restrict__ fw,
                                                   float* __restrict__ gain) {
    int p  = blockIdx.x * 256 + threadIdx.x;
    int py = p >> 7, px = p & 127;
    int fy = bitrev7(py), fx = bitrev7(px);
    int hy = (fy + 64) & 127, hx = (fx + 64) & 127;
    float dy = (float)(hy - 64), dx = (float)(hx - 64);
    float r = sqrtf(dy * dy + dx * dx);
    int ridx = (int)floorf(r * 0.125f);
    if (ridx > NRAD - 1) ridx = NRAD - 1;
    const float PI_F = 3.14159265358979323846f;
    float theta = fmodf(atan2f(dy, dx) + PI_F, PI_F);
    const float delta = (float)(M_PI / 8.0);
    const float hwid  = (float)(1.5 * (M_PI / 8.0) / 2.0);
    float wv[NANG];
    float wsum = 0.f;
#pragma unroll
    for (int a = 0; a < NANG; ++a) {
        float c = ((float)a + 0.5f) * delta;
        float dist = fabsf(theta - c);
        float wa = fmaxf(1.0f - dist / hwid, 0.0f);
        if (!(dist < hwid)) wa = 0.0f;
        wv[a] = wa;
        wsum += wa;
    }
    float inv = 1.0f / (wsum + 1e-8f);
#pragma unroll
    for (int m = 0; m < CMID; ++m) {
        float g = 0.f;
#pragma unroll
        for (int a = 0; a < NANG; ++a)
            g += wv[a] * fw[(m * NANG + a) * NRAD + ridx];
        gain[m * HWSZ + p] = g * inv * (1.0f / 16384.0f);
    }
}

// K2: split-K projection, float4 lanes. Block = (float4 px-tile, chunk, b).
__global__ void __launch_bounds__(256, 4) proj_partial(const float* __restrict__ x,
                                                       const float* __restrict__ w_in,
                                                       float* __restrict__ partials,
                                                       int nchunk) {
    int b  = blockIdx.z;
    int ck = blockIdx.y;
    int p4 = blockIdx.x * 256 + threadIdx.x;          // float4 index, 4096/image
    int cpc = CIN / nchunk;
    int c0 = ck * cpc;
    const float4* xb = (const float4*)(x + (size_t)b * CIN * HWSZ);
    float4 acc[CMID];
#pragma unroll
    for (int m = 0; m < CMID; ++m) acc[m] = make_float4(0.f, 0.f, 0.f, 0.f);
    for (int c = c0; c < c0 + cpc; c += 4) {
        float4 v0 = xb[(size_t)(c + 0) * HW4 + p4];
        float4 v1 = xb[(size_t)(c + 1) * HW4 + p4];
        float4 v2 = xb[(size_t)(c + 2) * HW4 + p4];
        float4 v3 = xb[(size_t)(c + 3) * HW4 + p4];
#pragma unroll
        for (int m = 0; m < CMID; ++m) {
            float w0 = w_in[m * CIN + c + 0];
            float w1 = w_in[m * CIN + c + 1];
            float w2 = w_in[m * CIN + c + 2];
            float w3 = w_in[m * CIN + c + 3];
            acc[m].x = fmaf(v0.x, w0, fmaf(v1.x, w1, fmaf(v2.x, w2, fmaf(v3.x, w3, acc[m].x))));
            acc[m].y = fmaf(v0.y, w0, fmaf(v1.y, w1, fmaf(v2.y, w2, fmaf(v3.y, w3, acc[m].y))));
            acc[m].z = fmaf(v0.z, w0, fmaf(v1.z, w1, fmaf(v2.z, w2, fmaf(v3.z, w3, acc[m].z))));
            acc[m].w = fmaf(v0.w, w0, fmaf(v1.w, w1, fmaf(v2.w, w2, fmaf(v3.w, w3, acc[m].w))));
        }
    }
    float4* pb = (float4*)(partials + ((size_t)(b * nchunk + ck) * CMID) * HWSZ);
#pragma unroll
    for (int m = 0; m < CMID; ++m) pb[(size_t)m * HW4 + p4] = acc[m];
}

// K3: reduce nchunk partials + forward row-DIF FFT. Block = 4 rows of one (b,m) image.
__global__ void __launch_bounds__(256) reduce_fft_rows(const float* __restrict__ partials,
                                                       float2* __restrict__ xf,
                                                       int nchunk) {
    __shared__ float2 lds[4 * 128];
    int img = blockIdx.y;                             // b*16 + m
    int b = img >> 4, m = img & 15;
    int r0 = blockIdx.x * 4;
    int t = threadIdx.x;
#pragma unroll
    for (int ii = 0; ii < 2; ++ii) {
        int px = ii * 256 + t;
        float s = 0.f;
        for (int ck = 0; ck < nchunk; ++ck)
            s += partials[((size_t)(b * nchunk + ck) * CMID + m) * HWSZ + r0 * NW + px];
        lds[px] = make_float2(s, 0.f);
    }
    __syncthreads();
    const float PI_F = 3.14159265358979323846f;
    int j = t & 63;
    float2* row = lds + (t >> 6) * 128;
    for (int ls = 6; ls >= 0; --ls) {
        int s = 1 << ls;
        int off = j & (s - 1);
        int i0 = ((j >> ls) << (ls + 1)) + off;
        float ang = -PI_F * (float)off / (float)s;
        float sn, cs;
        __sincosf(ang, &sn, &cs);
        float2 a = row[i0];
        float2 bb = row[i0 + s];
        row[i0] = make_float2(a.x + bb.x, a.y + bb.y);
        float dx_ = a.x - bb.x, dy_ = a.y - bb.y;
        row[i0 + s] = make_float2(dx_ * cs - dy_ * sn, dx_ * sn + dy_ * cs);
        __syncthreads();
    }
#pragma unroll
    for (int ii = 0; ii < 2; ++ii) {
        int px = ii * 256 + t;
        xf[(size_t)img * HWSZ + r0 * NW + px] = lds[px];
    }
}

// K4: forward col-DIF + gain + inverse col-DIT. Block = (32-col tile, image).
__global__ void __launch_bounds__(256) fft_cols_gain(float2* __restrict__ xf,
                                                     const float* __restrict__ gain) {
    __shared__ float2 buf[128 * 33];
    int img = blockIdx.y;
    int m   = img & (CMID - 1);
    int c0  = blockIdx.x * 32;
    int t   = threadIdx.x;
    float2* xi = xf + (size_t)img * HWSZ;

    for (int idx = t; idx < 128 * 32; idx += 256) {
        int r = idx >> 5, lc = idx & 31;
        buf[r * 33 + lc] = xi[r * NW + c0 + lc];
    }
    __syncthreads();
    const float PI_F = 3.14159265358979323846f;
    int lc = t & 31;
    int jb = t >> 5;
    for (int ls = 6; ls >= 0; --ls) {
        int s = 1 << ls;
        for (int j = jb; j < 64; j += 8) {
            int off = j & (s - 1);
            int i0 = ((j >> ls) << (ls + 1)) + off;
            float ang = -PI_F * (float)off / (float)s;
            float sn, cs;
            __sincosf(ang, &sn, &cs);
            float2 a = buf[i0 * 33 + lc];
            float2 bb = buf[(i0 + s) * 33 + lc];
            buf[i0 * 33 + lc] = make_float2(a.x + bb.x, a.y + bb.y);
            float dx_ = a.x - bb.x, dy_ = a.y - bb.y;
            buf[(i0 + s) * 33 + lc] = make_float2(dx_ * cs - dy_ * sn, dx_ * sn + dy_ * cs);
        }
        __syncthreads();
    }
    {
        const float* gm = gain + (size_t)m * HWSZ;
        for (int idx = t; idx < 128 * 32; idx += 256) {
            int r = idx >> 5, lcc = idx & 31;
            float g = gm[r * NW + c0 + lcc];
            buf[r * 33 + lcc].x *= g;
            buf[r * 33 + lcc].y *= g;
        }
        __syncthreads();
    }
    for (int ls = 0; ls <= 6; ++ls) {
        int s = 1 << ls;
        for (int j = jb; j < 64; j += 8) {
            int off = j & (s - 1);
            int i0 = ((j >> ls) << (ls + 1)) + off;
            float ang = PI_F * (float)off / (float)s;
            float sn, cs;
            __sincosf(ang, &sn, &cs);
            float2 a = buf[i0 * 33 + lc];
            float2 bb = buf[(i0 + s) * 33 + lc];
            float tx = bb.x * cs - bb.y * sn, ty = bb.x * sn + bb.y * cs;
            buf[i0 * 33 + lc] = make_float2(a.x + tx, a.y + ty);
            buf[(i0 + s) * 33 + lc] = make_float2(a.x - tx, a.y - ty);
        }
        __syncthreads();
    }
    for (int idx = t; idx < 128 * 32; idx += 256) {
        int r = idx >> 5, lcc = idx & 31;
        xi[r * NW + c0 + lcc] = buf[r * 33 + lcc];
    }
}

// K5: inverse row-DIT, write real x_enh. Block = 4 rows of one image.
__global__ void __launch_bounds__(256) ifft_rows(const float2* __restrict__ xf,
                                                 float* __restrict__ xe) {
    __shared__ float2 lds[4 * 128];
    int img = blockIdx.y;
    int r0 = blockIdx.x * 4;
    int t = threadIdx.x;
#pragma unroll
    for (int ii = 0; ii < 2; ++ii) {
        int px = ii * 256 + t;
        lds[px] = xf[(size_t)img * HWSZ + r0 * NW + px];
    }
    __syncthreads();
    const float PI_F = 3.14159265358979323846f;
    int j = t & 63;
    float2* row = lds + (t >> 6) * 128;
    for (int ls = 0; ls <= 6; ++ls) {
        int s = 1 << ls;
        int off = j & (s - 1);
        int i0 = ((j >> ls) << (ls + 1)) + off;
        float ang = PI_F * (float)off / (float)s;
        float sn, cs;
        __sincosf(ang, &sn, &cs);
        float2 a = row[i0];
        float2 bb = row[i0 + s];
        float tx = bb.x * cs - bb.y * sn, ty = bb.x * sn + bb.y * cs;
        row[i0] = make_float2(a.x + tx, a.y + ty);
        row[i0 + s] = make_float2(a.x - tx, a.y - ty);
        __syncthreads();
    }
#pragma unroll
    for (int ii = 0; ii < 2; ++ii) {
        int px = ii * 256 + t;
        xe[(size_t)img * HWSZ + r0 * NW + px] = lds[px].x;
    }
}

// K6: out = x + w_out * x_enh. float4 lanes, c-tile 32, nontemporal out stores.
__global__ void __launch_bounds__(256, 4) out_kernel(const float* __restrict__ x,
                                                     const float* __restrict__ w_out,
                                                     const float* __restrict__ xe,
                                                     float* __restrict__ out) {
    int b  = blockIdx.z;
    int ct = blockIdx.y;
    int p4 = blockIdx.x * 256 + threadIdx.x;
    const float4* xeb = (const float4*)(xe + (size_t)b * CMID * HWSZ);
    float4 e[CMID];
#pragma unroll
    for (int m = 0; m < CMID; ++m) e[m] = xeb[(size_t)m * HW4 + p4];
    const float4* xb = (const float4*)(x + (size_t)b * CIN * HWSZ);
    f32x4_t* ob = (f32x4_t*)(out + (size_t)b * CIN * HWSZ);
    int c0 = ct * 32;
    for (int c = c0; c < c0 + 32; c += 2) {
        float4 a0 = xb[(size_t)(c + 0) * HW4 + p4];
        float4 a1 = xb[(size_t)(c + 1) * HW4 + p4];
#pragma unroll
        for (int m = 0; m < CMID; ++m) {
            float w0 = w_out[(c + 0) * CMID + m];
            float w1 = w_out[(c + 1) * CMID + m];
            a0.x = fmaf(w0, e[m].x, a0.x); a0.y = fmaf(w0, e[m].y, a0.y);
            a0.z = fmaf(w0, e[m].z, a0.z); a0.w = fmaf(w0, e[m].w, a0.w);
            a1.x = fmaf(w1, e[m].x, a1.x); a1.y = fmaf(w1, e[m].y, a1.y);
            a1.z = fmaf(w1, e[m].z, a1.z); a1.w = fmaf(w1, e[m].w, a1.w);
        }
        f32x4_t s0 = { a0.x, a0.y, a0.z, a0.w };
        f32x4_t s1 = { a1.x, a1.y, a1.z, a1.w };
        __builtin_nontemporal_store(s0, ob + (size_t)(c + 0) * HW4 + p4);
        __builtin_nontemporal_store(s1, ob + (size_t)(c + 1) * HW4 + p4);
    }
}

extern "C" void kernel_launch(void* const* d_in, const int* in_sizes, int n_in,
                              void* d_out, int out_size, void* d_ws, size_t ws_size,
                              hipStream_t stream) {
    const float* x     = (const float*)d_in[0];
    const float* w_in  = (const float*)d_in[1];
    const float* w_out = (const float*)d_in[2];
    const float* fw    = (const float*)d_in[3];
    float* out = (float*)d_out;
    float* ws  = (float*)d_ws;

    int nchunk = 8;
    while (nchunk > 1) {
        size_t need = ((size_t)NB * nchunk * CMID * HWSZ +
                       (size_t)NB * CMID * HWSZ * 2 + (size_t)CMID * HWSZ) * sizeof(float);
        if (need <= ws_size) break;
        nchunk >>= 1;
    }
    float*  partials = ws;
    float2* xf   = (float2*)(ws + (size_t)NB * nchunk * CMID * HWSZ);
    float*  gain = (float*)(xf + (size_t)NB * CMID * HWSZ);
    float*  xe   = partials;                          // reuse after K3 consumes partials

    gain_kernel<<<HWSZ / 256, 256, 0, stream>>>(fw, gain);
    proj_partial<<<dim3(HW4 / 256, nchunk, NB), 256, 0, stream>>>(x, w_in, partials, nchunk);
    reduce_fft_rows<<<dim3(NH / 4, NB * CMID), 256, 0, stream>>>(partials, xf, nchunk);
    fft_cols_gain<<<dim3(NW / 32, NB * CMID), 256, 0, stream>>>(xf, gain);
    ifft_rows<<<dim3(NH / 4, NB * CMID), 256, 0, stream>>>(xf, xe);
    out_kernel<<<dim3(HW4 / 256, CIN / 32, NB), 256, 0, stream>>>(x, w_out, xe, out);
}

// Round 6
// 126.418 us; speedup vs baseline: 1.4480x; 1.0369x over previous
//
#include <hip/hip_runtime.h>
#include <math.h>

#define NB   8
#define CIN  256
#define CMID 16
#define NH   128
#define NW   128
#define HWSZ 16384
#define HW4  4096
#define NANG 8
#define NRAD 9

typedef float    f32x4_t __attribute__((ext_vector_type(4)));
typedef unsigned u32x2_t __attribute__((ext_vector_type(2)));

__device__ __forceinline__ unsigned short f2bf(float f) {
    unsigned u = __float_as_uint(f);
    u += 0x7fffu + ((u >> 16) & 1u);          // round-to-nearest-even
    return (unsigned short)(u >> 16);
}
__device__ __forceinline__ float bf_lo(unsigned u) { return __uint_as_float(u << 16); }
__device__ __forceinline__ float bf_hi(unsigned u) { return __uint_as_float(u & 0xffff0000u); }
__device__ __forceinline__ unsigned pack2(float a, float b) {
    return (unsigned)f2bf(a) | ((unsigned)f2bf(b) << 16);
}

__device__ __forceinline__ int bitrev7(int v) {
    return (int)(__brev((unsigned)v) >> 25);
}

// Gain in bit-reversed (both dims), ifftshift-folded order, pre-scaled by 1/16384.
__global__ void __launch_bounds__(256) gain_kernel(const float* __restrict__ fw,
                                                   float* __restrict__ gain) {
    int p  = blockIdx.x * 256 + threadIdx.x;
    int py = p >> 7, px = p & 127;
    int fy = bitrev7(py), fx = bitrev7(px);
    int hy = (fy + 64) & 127, hx = (fx + 64) & 127;
    float dy = (float)(hy - 64), dx = (float)(hx - 64);
    float r = sqrtf(dy * dy + dx * dx);
    int ridx = (int)floorf(r * 0.125f);
    if (ridx > NRAD - 1) ridx = NRAD - 1;
    const float PI_F = 3.14159265358979323846f;
    float theta = fmodf(atan2f(dy, dx) + PI_F, PI_F);
    const float delta = (float)(M_PI / 8.0);
    const float hwid  = (float)(1.5 * (M_PI / 8.0) / 2.0);
    float wv[NANG];
    float wsum = 0.f;
#pragma unroll
    for (int a = 0; a < NANG; ++a) {
        float c = ((float)a + 0.5f) * delta;
        float dist = fabsf(theta - c);
        float wa = fmaxf(1.0f - dist / hwid, 0.0f);
        if (!(dist < hwid)) wa = 0.0f;
        wv[a] = wa;
        wsum += wa;
    }
    float inv = 1.0f / (wsum + 1e-8f);
#pragma unroll
    for (int m = 0; m < CMID; ++m) {
        float g = 0.f;
#pragma unroll
        for (int a = 0; a < NANG; ++a)
            g += wv[a] * fw[(m * NANG + a) * NRAD + ridx];
        gain[m * HWSZ + p] = g * inv * (1.0f / 16384.0f);
    }
}

// K2: split-K projection, float4 lanes, bf16 partial stores.
__global__ void __launch_bounds__(256, 4) proj_partial(const float* __restrict__ x,
                                                       const float* __restrict__ w_in,
                                                       unsigned short* __restrict__ partials,
                                                       int nchunk) {
    int b  = blockIdx.z;
    int ck = blockIdx.y;
    int p4 = blockIdx.x * 256 + threadIdx.x;          // float4 index, 4096/image
    int cpc = CIN / nchunk;
    int c0 = ck * cpc;
    const float4* xb = (const float4*)(x + (size_t)b * CIN * HWSZ);
    float4 acc[CMID];
#pragma unroll
    for (int m = 0; m < CMID; ++m) acc[m] = make_float4(0.f, 0.f, 0.f, 0.f);
    for (int c = c0; c < c0 + cpc; c += 4) {
        float4 v0 = xb[(size_t)(c + 0) * HW4 + p4];
        float4 v1 = xb[(size_t)(c + 1) * HW4 + p4];
        float4 v2 = xb[(size_t)(c + 2) * HW4 + p4];
        float4 v3 = xb[(size_t)(c + 3) * HW4 + p4];
#pragma unroll
        for (int m = 0; m < CMID; ++m) {
            float w0 = w_in[m * CIN + c + 0];
            float w1 = w_in[m * CIN + c + 1];
            float w2 = w_in[m * CIN + c + 2];
            float w3 = w_in[m * CIN + c + 3];
            acc[m].x = fmaf(v0.x, w0, fmaf(v1.x, w1, fmaf(v2.x, w2, fmaf(v3.x, w3, acc[m].x))));
            acc[m].y = fmaf(v0.y, w0, fmaf(v1.y, w1, fmaf(v2.y, w2, fmaf(v3.y, w3, acc[m].y))));
            acc[m].z = fmaf(v0.z, w0, fmaf(v1.z, w1, fmaf(v2.z, w2, fmaf(v3.z, w3, acc[m].z))));
            acc[m].w = fmaf(v0.w, w0, fmaf(v1.w, w1, fmaf(v2.w, w2, fmaf(v3.w, w3, acc[m].w))));
        }
    }
    ushort4* pb = (ushort4*)partials + ((size_t)(b * nchunk + ck) * CMID) * HW4;
#pragma unroll
    for (int m = 0; m < CMID; ++m)
        pb[(size_t)m * HW4 + p4] = make_ushort4(f2bf(acc[m].x), f2bf(acc[m].y),
                                                f2bf(acc[m].z), f2bf(acc[m].w));
}

// K3: reduce bf16 partials (NT last-use loads) + forward row-DIF FFT.
// Block = 4 rows of one (b,m) image; thread t owns px pair {2t, 2t+1} of the strip.
__global__ void __launch_bounds__(256) reduce_fft_rows(const unsigned short* __restrict__ partials,
                                                       unsigned* __restrict__ xf,
                                                       int nchunk) {
    __shared__ float2 lds[512];
    int img = blockIdx.y;                             // b*16 + m
    int b = img >> 4, m = img & 15;
    int r0 = blockIdx.x * 4;
    int t = threadIdx.x;
    const unsigned* pbase = (const unsigned*)(partials +
        ((size_t)(b * nchunk) * CMID + m) * HWSZ + (size_t)r0 * NW) + t;
    size_t cks = (size_t)CMID * HWSZ / 2;             // uints per chunk
    float sx = 0.f, sy = 0.f;
    if (nchunk == 8) {
#pragma unroll
        for (int ck = 0; ck < 8; ++ck) {
            unsigned u = __builtin_nontemporal_load(pbase + (size_t)ck * cks);
            sx += bf_lo(u); sy += bf_hi(u);
        }
    } else {
        for (int ck = 0; ck < nchunk; ++ck) {
            unsigned u = __builtin_nontemporal_load(pbase + (size_t)ck * cks);
            sx += bf_lo(u); sy += bf_hi(u);
        }
    }
    lds[2 * t]     = make_float2(sx, 0.f);
    lds[2 * t + 1] = make_float2(sy, 0.f);
    __syncthreads();
    const float PI_F = 3.14159265358979323846f;
    int j = t & 63;
    float2* row = lds + (t >> 6) * 128;
    for (int ls = 6; ls >= 0; --ls) {
        int s = 1 << ls;
        int off = j & (s - 1);
        int i0 = ((j >> ls) << (ls + 1)) + off;
        float ang = -PI_F * (float)off / (float)s;
        float sn, cs;
        __sincosf(ang, &sn, &cs);
        float2 a = row[i0];
        float2 bb = row[i0 + s];
        row[i0] = make_float2(a.x + bb.x, a.y + bb.y);
        float dx_ = a.x - bb.x, dy_ = a.y - bb.y;
        row[i0 + s] = make_float2(dx_ * cs - dy_ * sn, dx_ * sn + dy_ * cs);
        __syncthreads();
    }
    unsigned* xo = xf + (size_t)img * HWSZ + (size_t)r0 * NW;
#pragma unroll
    for (int ii = 0; ii < 2; ++ii) {
        int px = ii * 256 + t;
        xo[px] = pack2(lds[px].x, lds[px].y);
    }
}

// K4: forward col-DIF + gain + inverse col-DIT on bf16-complex xf (in place).
__global__ void __launch_bounds__(256) fft_cols_gain(unsigned* __restrict__ xf,
                                                     const float* __restrict__ gain) {
    __shared__ float2 buf[128 * 33];
    int img = blockIdx.y;
    int m   = img & (CMID - 1);
    int c0  = blockIdx.x * 32;
    int t   = threadIdx.x;
    unsigned* xi = xf + (size_t)img * HWSZ;

    for (int idx = t; idx < 128 * 32; idx += 256) {
        int r = idx >> 5, lc = idx & 31;
        unsigned u = __builtin_nontemporal_load(&xi[r * NW + c0 + lc]);
        buf[r * 33 + lc] = make_float2(bf_lo(u), bf_hi(u));
    }
    __syncthreads();
    const float PI_F = 3.14159265358979323846f;
    int lc = t & 31;
    int jb = t >> 5;
    for (int ls = 6; ls >= 0; --ls) {
        int s = 1 << ls;
        for (int j = jb; j < 64; j += 8) {
            int off = j & (s - 1);
            int i0 = ((j >> ls) << (ls + 1)) + off;
            float ang = -PI_F * (float)off / (float)s;
            float sn, cs;
            __sincosf(ang, &sn, &cs);
            float2 a = buf[i0 * 33 + lc];
            float2 bb = buf[(i0 + s) * 33 + lc];
            buf[i0 * 33 + lc] = make_float2(a.x + bb.x, a.y + bb.y);
            float dx_ = a.x - bb.x, dy_ = a.y - bb.y;
            buf[(i0 + s) * 33 + lc] = make_float2(dx_ * cs - dy_ * sn, dx_ * sn + dy_ * cs);
        }
        __syncthreads();
    }
    {
        const float* gm = gain + (size_t)m * HWSZ;
        for (int idx = t; idx < 128 * 32; idx += 256) {
            int r = idx >> 5, lcc = idx & 31;
            float g = gm[r * NW + c0 + lcc];
            buf[r * 33 + lcc].x *= g;
            buf[r * 33 + lcc].y *= g;
        }
        __syncthreads();
    }
    for (int ls = 0; ls <= 6; ++ls) {
        int s = 1 << ls;
        for (int j = jb; j < 64; j += 8) {
            int off = j & (s - 1);
            int i0 = ((j >> ls) << (ls + 1)) + off;
            float ang = PI_F * (float)off / (float)s;
            float sn, cs;
            __sincosf(ang, &sn, &cs);
            float2 a = buf[i0 * 33 + lc];
            float2 bb = buf[(i0 + s) * 33 + lc];
            float tx = bb.x * cs - bb.y * sn, ty = bb.x * sn + bb.y * cs;
            buf[i0 * 33 + lc] = make_float2(a.x + tx, a.y + ty);
            buf[(i0 + s) * 33 + lc] = make_float2(a.x - tx, a.y - ty);
        }
        __syncthreads();
    }
    for (int idx = t; idx < 128 * 32; idx += 256) {
        int r = idx >> 5, lcc = idx & 31;
        xi[r * NW + c0 + lcc] = pack2(buf[r * 33 + lcc].x, buf[r * 33 + lcc].y);
    }
}

// K5: inverse row-DIT, write real x_enh as bf16. Block = 4 rows of one image.
__global__ void __launch_bounds__(256) ifft_rows(const unsigned* __restrict__ xf,
                                                 unsigned short* __restrict__ xe) {
    __shared__ float2 lds[512];
    int img = blockIdx.y;
    int r0 = blockIdx.x * 4;
    int t = threadIdx.x;
    const unsigned* xi = xf + (size_t)img * HWSZ + (size_t)r0 * NW;
#pragma unroll
    for (int ii = 0; ii < 2; ++ii) {
        int px = ii * 256 + t;
        unsigned u = __builtin_nontemporal_load(&xi[px]);
        lds[px] = make_float2(bf_lo(u), bf_hi(u));
    }
    __syncthreads();
    const float PI_F = 3.14159265358979323846f;
    int j = t & 63;
    float2* row = lds + (t >> 6) * 128;
    for (int ls = 0; ls <= 6; ++ls) {
        int s = 1 << ls;
        int off = j & (s - 1);
        int i0 = ((j >> ls) << (ls + 1)) + off;
        float ang = PI_F * (float)off / (float)s;
        float sn, cs;
        __sincosf(ang, &sn, &cs);
        float2 a = row[i0];
        float2 bb = row[i0 + s];
        float tx = bb.x * cs - bb.y * sn, ty = bb.x * sn + bb.y * cs;
        row[i0] = make_float2(a.x + tx, a.y + ty);
        row[i0 + s] = make_float2(a.x - tx, a.y - ty);
        __syncthreads();
    }
    unsigned* xo = (unsigned*)xe + (((size_t)img * HWSZ + (size_t)r0 * NW) >> 1) + t;
    xo[0] = pack2(lds[2 * t].x, lds[2 * t + 1].x);
}

// K6: out = x + w_out * x_enh. NT last-use loads of x and xe; NT out stores.
__global__ void __launch_bounds__(256, 4) out_kernel(const float* __restrict__ x,
                                                     const float* __restrict__ w_out,
                                                     const unsigned short* __restrict__ xe,
                                                     float* __restrict__ out) {
    int b  = blockIdx.z;
    int ct = blockIdx.y;
    int p4 = blockIdx.x * 256 + threadIdx.x;
    const u32x2_t* xeb = (const u32x2_t*)(xe + (size_t)b * CMID * HWSZ);
    f32x4_t e[CMID];
#pragma unroll
    for (int m = 0; m < CMID; ++m) {
        u32x2_t u = __builtin_nontemporal_load(&xeb[(size_t)m * HW4 + p4]);
        e[m] = (f32x4_t){ bf_lo(u.x), bf_hi(u.x), bf_lo(u.y), bf_hi(u.y) };
    }
    const f32x4_t* xb = (const f32x4_t*)(x + (size_t)b * CIN * HWSZ);
    f32x4_t* ob = (f32x4_t*)(out + (size_t)b * CIN * HWSZ);
    int c0 = ct * 32;
    for (int c = c0; c < c0 + 32; c += 2) {
        f32x4_t a0 = __builtin_nontemporal_load(xb + (size_t)(c + 0) * HW4 + p4);
        f32x4_t a1 = __builtin_nontemporal_load(xb + (size_t)(c + 1) * HW4 + p4);
#pragma unroll
        for (int m = 0; m < CMID; ++m) {
            a0 += w_out[(c + 0) * CMID + m] * e[m];
            a1 += w_out[(c + 1) * CMID + m] * e[m];
        }
        __builtin_nontemporal_store(a0, ob + (size_t)(c + 0) * HW4 + p4);
        __builtin_nontemporal_store(a1, ob + (size_t)(c + 1) * HW4 + p4);
    }
}

extern "C" void kernel_launch(void* const* d_in, const int* in_sizes, int n_in,
                              void* d_out, int out_size, void* d_ws, size_t ws_size,
                              hipStream_t stream) {
    const float* x     = (const float*)d_in[0];
    const float* w_in  = (const float*)d_in[1];
    const float* w_out = (const float*)d_in[2];
    const float* fw    = (const float*)d_in[3];
    float* out = (float*)d_out;

    int nchunk = 8;
    while (nchunk > 1) {
        size_t need = (size_t)NB * nchunk * CMID * HWSZ * 2   // partials bf16
                    + (size_t)NB * CMID * HWSZ * 4            // xf bf16-complex
                    + (size_t)CMID * HWSZ * 4;                // gain fp32
        if (need <= ws_size) break;
        nchunk >>= 1;
    }
    unsigned short* partials = (unsigned short*)d_ws;
    unsigned* xfu = (unsigned*)(partials + (size_t)NB * nchunk * CMID * HWSZ);
    float*    gain = (float*)(xfu + (size_t)NB * CMID * HWSZ);
    unsigned short* xe = partials;                    // reuse (4 MB ≤ partials size)

    gain_kernel<<<HWSZ / 256, 256, 0, stream>>>(fw, gain);
    proj_partial<<<dim3(HW4 / 256, nchunk, NB), 256, 0, stream>>>(x, w_in, partials, nchunk);
    reduce_fft_rows<<<dim3(NH / 4, NB * CMID), 256, 0, stream>>>(partials, xfu, nchunk);
    fft_cols_gain<<<dim3(NW / 32, NB * CMID), 256, 0, stream>>>(xfu, gain);
    ifft_rows<<<dim3(NH / 4, NB * CMID), 256, 0, stream>>>(xfu, xe);
    out_kernel<<<dim3(HW4 / 256, CIN / 32, NB), 256, 0, stream>>>(x, w_out, xe, out);
}

// Round 7
// 116.472 us; speedup vs baseline: 1.5717x; 1.0854x over previous
//
#include <hip/hip_runtime.h>
#include <math.h>

#define NB   8
#define CIN  256
#define CMID 16
#define NH   128
#define NW   128
#define HWSZ 16384
#define HW4  4096
#define NANG 8
#define NRAD 9

typedef float    f32x4_t __attribute__((ext_vector_type(4)));
typedef unsigned u32x2_t __attribute__((ext_vector_type(2)));

__device__ __forceinline__ unsigned short f2bf(float f) {
    unsigned u = __float_as_uint(f);
    u += 0x7fffu + ((u >> 16) & 1u);          // round-to-nearest-even
    return (unsigned short)(u >> 16);
}
__device__ __forceinline__ float bf_lo(unsigned u) { return __uint_as_float(u << 16); }
__device__ __forceinline__ float bf_hi(unsigned u) { return __uint_as_float(u & 0xffff0000u); }
__device__ __forceinline__ unsigned pack2(float a, float b) {
    return (unsigned)f2bf(a) | ((unsigned)f2bf(b) << 16);
}

__device__ __forceinline__ int bitrev7(int v) {
    return (int)(__brev((unsigned)v) >> 25);
}

// Gain in bit-reversed (both dims), ifftshift-folded order, pre-scaled by 1/16384.
__global__ void __launch_bounds__(256) gain_kernel(const float* __restrict__ fw,
                                                   float* __restrict__ gain) {
    int p  = blockIdx.x * 256 + threadIdx.x;
    int py = p >> 7, px = p & 127;
    int fy = bitrev7(py), fx = bitrev7(px);
    int hy = (fy + 64) & 127, hx = (fx + 64) & 127;
    float dy = (float)(hy - 64), dx = (float)(hx - 64);
    float r = sqrtf(dy * dy + dx * dx);
    int ridx = (int)floorf(r * 0.125f);
    if (ridx > NRAD - 1) ridx = NRAD - 1;
    const float PI_F = 3.14159265358979323846f;
    float theta = fmodf(atan2f(dy, dx) + PI_F, PI_F);
    const float delta = (float)(M_PI / 8.0);
    const float hwid  = (float)(1.5 * (M_PI / 8.0) / 2.0);
    float wv[NANG];
    float wsum = 0.f;
#pragma unroll
    for (int a = 0; a < NANG; ++a) {
        float c = ((float)a + 0.5f) * delta;
        float dist = fabsf(theta - c);
        float wa = fmaxf(1.0f - dist / hwid, 0.0f);
        if (!(dist < hwid)) wa = 0.0f;
        wv[a] = wa;
        wsum += wa;
    }
    float inv = 1.0f / (wsum + 1e-8f);
#pragma unroll
    for (int m = 0; m < CMID; ++m) {
        float g = 0.f;
#pragma unroll
        for (int a = 0; a < NANG; ++a)
            g += wv[a] * fw[(m * NANG + a) * NRAD + ridx];
        gain[m * HWSZ + p] = g * inv * (1.0f / 16384.0f);
    }
}

// K2: split-K projection, float4 lanes, 8 loads in flight, bf16 partial stores.
__global__ void __launch_bounds__(256, 4) proj_partial(const float* __restrict__ x,
                                                       const float* __restrict__ w_in,
                                                       unsigned short* __restrict__ partials,
                                                       int nchunk) {
    int b  = blockIdx.z;
    int ck = blockIdx.y;
    int p4 = blockIdx.x * 256 + threadIdx.x;          // float4 index, 4096/image
    int cpc = CIN / nchunk;
    int c0 = ck * cpc;
    const f32x4_t* xb = (const f32x4_t*)(x + (size_t)b * CIN * HWSZ);
    f32x4_t acc[CMID];
#pragma unroll
    for (int m = 0; m < CMID; ++m) acc[m] = (f32x4_t){0.f, 0.f, 0.f, 0.f};
    for (int c = c0; c < c0 + cpc; c += 8) {
        f32x4_t v[8];
#pragma unroll
        for (int k = 0; k < 8; ++k)
            v[k] = xb[(size_t)(c + k) * HW4 + p4];
#pragma unroll
        for (int k = 0; k < 8; ++k) {
#pragma unroll
            for (int m = 0; m < CMID; ++m)
                acc[m] += w_in[m * CIN + c + k] * v[k];
        }
    }
    ushort4* pb = (ushort4*)partials + ((size_t)(b * nchunk + ck) * CMID) * HW4;
#pragma unroll
    for (int m = 0; m < CMID; ++m)
        pb[(size_t)m * HW4 + p4] = make_ushort4(f2bf(acc[m].x), f2bf(acc[m].y),
                                                f2bf(acc[m].z), f2bf(acc[m].w));
}

// K3: reduce bf16 partials + forward row-DIF FFT.
// Block = 4 rows of one (b,m) image; thread t owns px pair {2t, 2t+1} of the strip.
__global__ void __launch_bounds__(256) reduce_fft_rows(const unsigned short* __restrict__ partials,
                                                       unsigned* __restrict__ xf,
                                                       int nchunk) {
    __shared__ float2 lds[512];
    int img = blockIdx.y;                             // b*16 + m
    int b = img >> 4, m = img & 15;
    int r0 = blockIdx.x * 4;
    int t = threadIdx.x;
    const unsigned* pbase = (const unsigned*)(partials +
        ((size_t)(b * nchunk) * CMID + m) * HWSZ + (size_t)r0 * NW) + t;
    size_t cks = (size_t)CMID * HWSZ / 2;             // uints per chunk
    float sx = 0.f, sy = 0.f;
    if (nchunk == 8) {
#pragma unroll
        for (int ck = 0; ck < 8; ++ck) {
            unsigned u = pbase[(size_t)ck * cks];
            sx += bf_lo(u); sy += bf_hi(u);
        }
    } else {
        for (int ck = 0; ck < nchunk; ++ck) {
            unsigned u = pbase[(size_t)ck * cks];
            sx += bf_lo(u); sy += bf_hi(u);
        }
    }
    lds[2 * t]     = make_float2(sx, 0.f);
    lds[2 * t + 1] = make_float2(sy, 0.f);
    __syncthreads();
    const float PI_F = 3.14159265358979323846f;
    int j = t & 63;
    float2* row = lds + (t >> 6) * 128;
    for (int ls = 6; ls >= 0; --ls) {
        int s = 1 << ls;
        int off = j & (s - 1);
        int i0 = ((j >> ls) << (ls + 1)) + off;
        float ang = -PI_F * (float)off / (float)s;
        float sn, cs;
        __sincosf(ang, &sn, &cs);
        float2 a = row[i0];
        float2 bb = row[i0 + s];
        row[i0] = make_float2(a.x + bb.x, a.y + bb.y);
        float dx_ = a.x - bb.x, dy_ = a.y - bb.y;
        row[i0 + s] = make_float2(dx_ * cs - dy_ * sn, dx_ * sn + dy_ * cs);
        __syncthreads();
    }
    unsigned* xo = xf + (size_t)img * HWSZ + (size_t)r0 * NW;
#pragma unroll
    for (int ii = 0; ii < 2; ++ii) {
        int px = ii * 256 + t;
        xo[px] = pack2(lds[px].x, lds[px].y);
    }
}

// K4: forward col-DIF + gain + inverse col-DIT on bf16-complex xf (in place).
__global__ void __launch_bounds__(256) fft_cols_gain(unsigned* __restrict__ xf,
                                                     const float* __restrict__ gain) {
    __shared__ float2 buf[128 * 33];
    int img = blockIdx.y;
    int m   = img & (CMID - 1);
    int c0  = blockIdx.x * 32;
    int t   = threadIdx.x;
    unsigned* xi = xf + (size_t)img * HWSZ;

    for (int idx = t; idx < 128 * 32; idx += 256) {
        int r = idx >> 5, lc = idx & 31;
        unsigned u = xi[r * NW + c0 + lc];
        buf[r * 33 + lc] = make_float2(bf_lo(u), bf_hi(u));
    }
    __syncthreads();
    const float PI_F = 3.14159265358979323846f;
    int lc = t & 31;
    int jb = t >> 5;
    for (int ls = 6; ls >= 0; --ls) {
        int s = 1 << ls;
        for (int j = jb; j < 64; j += 8) {
            int off = j & (s - 1);
            int i0 = ((j >> ls) << (ls + 1)) + off;
            float ang = -PI_F * (float)off / (float)s;
            float sn, cs;
            __sincosf(ang, &sn, &cs);
            float2 a = buf[i0 * 33 + lc];
            float2 bb = buf[(i0 + s) * 33 + lc];
            buf[i0 * 33 + lc] = make_float2(a.x + bb.x, a.y + bb.y);
            float dx_ = a.x - bb.x, dy_ = a.y - bb.y;
            buf[(i0 + s) * 33 + lc] = make_float2(dx_ * cs - dy_ * sn, dx_ * sn + dy_ * cs);
        }
        __syncthreads();
    }
    {
        const float* gm = gain + (size_t)m * HWSZ;
        for (int idx = t; idx < 128 * 32; idx += 256) {
            int r = idx >> 5, lcc = idx & 31;
            float g = gm[r * NW + c0 + lcc];
            buf[r * 33 + lcc].x *= g;
            buf[r * 33 + lcc].y *= g;
        }
        __syncthreads();
    }
    for (int ls = 0; ls <= 6; ++ls) {
        int s = 1 << ls;
        for (int j = jb; j < 64; j += 8) {
            int off = j & (s - 1);
            int i0 = ((j >> ls) << (ls + 1)) + off;
            float ang = PI_F * (float)off / (float)s;
            float sn, cs;
            __sincosf(ang, &sn, &cs);
            float2 a = buf[i0 * 33 + lc];
            float2 bb = buf[(i0 + s) * 33 + lc];
            float tx = bb.x * cs - bb.y * sn, ty = bb.x * sn + bb.y * cs;
            buf[i0 * 33 + lc] = make_float2(a.x + tx, a.y + ty);
            buf[(i0 + s) * 33 + lc] = make_float2(a.x - tx, a.y - ty);
        }
        __syncthreads();
    }
    for (int idx = t; idx < 128 * 32; idx += 256) {
        int r = idx >> 5, lcc = idx & 31;
        xi[r * NW + c0 + lcc] = pack2(buf[r * 33 + lcc].x, buf[r * 33 + lcc].y);
    }
}

// K5: inverse row-DIT, write real x_enh as bf16. Block = 4 rows of one image.
__global__ void __launch_bounds__(256) ifft_rows(const unsigned* __restrict__ xf,
                                                 unsigned short* __restrict__ xe) {
    __shared__ float2 lds[512];
    int img = blockIdx.y;
    int r0 = blockIdx.x * 4;
    int t = threadIdx.x;
    const unsigned* xi = xf + (size_t)img * HWSZ + (size_t)r0 * NW;
#pragma unroll
    for (int ii = 0; ii < 2; ++ii) {
        int px = ii * 256 + t;
        unsigned u = xi[px];
        lds[px] = make_float2(bf_lo(u), bf_hi(u));
    }
    __syncthreads();
    const float PI_F = 3.14159265358979323846f;
    int j = t & 63;
    float2* row = lds + (t >> 6) * 128;
    for (int ls = 0; ls <= 6; ++ls) {
        int s = 1 << ls;
        int off = j & (s - 1);
        int i0 = ((j >> ls) << (ls + 1)) + off;
        float ang = PI_F * (float)off / (float)s;
        float sn, cs;
        __sincosf(ang, &sn, &cs);
        float2 a = row[i0];
        float2 bb = row[i0 + s];
        float tx = bb.x * cs - bb.y * sn, ty = bb.x * sn + bb.y * cs;
        row[i0] = make_float2(a.x + tx, a.y + ty);
        row[i0 + s] = make_float2(a.x - tx, a.y - ty);
        __syncthreads();
    }
    unsigned* xo = (unsigned*)xe + (((size_t)img * HWSZ + (size_t)r0 * NW) >> 1) + t;
    xo[0] = pack2(lds[2 * t].x, lds[2 * t + 1].x);
}

// K6: out = x + w_out * x_enh. c-tile 16 (grid 2048), 4 loads in flight, NT out stores.
__global__ void __launch_bounds__(256, 4) out_kernel(const float* __restrict__ x,
                                                     const float* __restrict__ w_out,
                                                     const unsigned short* __restrict__ xe,
                                                     float* __restrict__ out) {
    int b  = blockIdx.z;
    int ct = blockIdx.y;
    int p4 = blockIdx.x * 256 + threadIdx.x;
    const u32x2_t* xeb = (const u32x2_t*)(xe + (size_t)b * CMID * HWSZ);
    f32x4_t e[CMID];
#pragma unroll
    for (int m = 0; m < CMID; ++m) {
        u32x2_t u = xeb[(size_t)m * HW4 + p4];
        e[m] = (f32x4_t){ bf_lo(u.x), bf_hi(u.x), bf_lo(u.y), bf_hi(u.y) };
    }
    const f32x4_t* xb = (const f32x4_t*)(x + (size_t)b * CIN * HWSZ);
    f32x4_t* ob = (f32x4_t*)(out + (size_t)b * CIN * HWSZ);
    int c0 = ct * 16;
    for (int c = c0; c < c0 + 16; c += 4) {
        f32x4_t a0 = xb[(size_t)(c + 0) * HW4 + p4];
        f32x4_t a1 = xb[(size_t)(c + 1) * HW4 + p4];
        f32x4_t a2 = xb[(size_t)(c + 2) * HW4 + p4];
        f32x4_t a3 = xb[(size_t)(c + 3) * HW4 + p4];
#pragma unroll
        for (int m = 0; m < CMID; ++m) {
            a0 += w_out[(c + 0) * CMID + m] * e[m];
            a1 += w_out[(c + 1) * CMID + m] * e[m];
            a2 += w_out[(c + 2) * CMID + m] * e[m];
            a3 += w_out[(c + 3) * CMID + m] * e[m];
        }
        __builtin_nontemporal_store(a0, ob + (size_t)(c + 0) * HW4 + p4);
        __builtin_nontemporal_store(a1, ob + (size_t)(c + 1) * HW4 + p4);
        __builtin_nontemporal_store(a2, ob + (size_t)(c + 2) * HW4 + p4);
        __builtin_nontemporal_store(a3, ob + (size_t)(c + 3) * HW4 + p4);
    }
}

extern "C" void kernel_launch(void* const* d_in, const int* in_sizes, int n_in,
                              void* d_out, int out_size, void* d_ws, size_t ws_size,
                              hipStream_t stream) {
    const float* x     = (const float*)d_in[0];
    const float* w_in  = (const float*)d_in[1];
    const float* w_out = (const float*)d_in[2];
    const float* fw    = (const float*)d_in[3];
    float* out = (float*)d_out;

    int nchunk = 8;
    while (nchunk > 1) {
        size_t need = (size_t)NB * nchunk * CMID * HWSZ * 2   // partials bf16
                    + (size_t)NB * CMID * HWSZ * 4            // xf bf16-complex
                    + (size_t)CMID * HWSZ * 4;                // gain fp32
        if (need <= ws_size) break;
        nchunk >>= 1;
    }
    unsigned short* partials = (unsigned short*)d_ws;
    unsigned* xfu = (unsigned*)(partials + (size_t)NB * nchunk * CMID * HWSZ);
    float*    gain = (float*)(xfu + (size_t)NB * CMID * HWSZ);
    unsigned short* xe = partials;                    // reuse (4 MB ≤ partials size)

    gain_kernel<<<HWSZ / 256, 256, 0, stream>>>(fw, gain);
    proj_partial<<<dim3(HW4 / 256, nchunk, NB), 256, 0, stream>>>(x, w_in, partials, nchunk);
    reduce_fft_rows<<<dim3(NH / 4, NB * CMID), 256, 0, stream>>>(partials, xfu, nchunk);
    fft_cols_gain<<<dim3(NW / 32, NB * CMID), 256, 0, stream>>>(xfu, gain);
    ifft_rows<<<dim3(NH / 4, NB * CMID), 256, 0, stream>>>(xfu, xe);
    out_kernel<<<dim3(HW4 / 256, CIN / 16, NB), 256, 0, stream>>>(x, w_out, xe, out);
}